// Round 19
// baseline (305.912 us; speedup 1.0000x reference)
//
#include <hip/hip_runtime.h>

static constexpr int D = 96;       // hidden size
static constexpr int G3 = 3 * D;   // 288 gate rows
static constexpr int NSTEPS = 4;   // GGNN propagation steps
static constexpr int NT = 18;      // 288/16 col-tiles per weight matrix
static constexpr int SLP = 104;    // s-tile LDS row pad (fp16)
static constexpr int PLS = 97;     // plane row stride (dwords)
static constexpr int PLANE = 16 * PLS;
static constexpr int CAP = 24576;  // staging capacity per 1024-node bucket
static constexpr int ELP = 100;    // elu(h') LDS row pad (fp16)

typedef __attribute__((ext_vector_type(8))) _Float16 f16x8;  // 8 fp16 (4 VGPRs)
typedef __attribute__((ext_vector_type(4))) _Float16 f16x4;
typedef __attribute__((ext_vector_type(4))) float f32x4;     // MFMA C/D frag

// A-fragment for mfma_f32_16x16x32_f16 from fp16 row-major [*,96]
__device__ __forceinline__ f16x8 load_a_frag(const _Float16* __restrict__ base,
                                             int r0, int lane, int kc) {
  int row = r0 + (lane & 15);
  int k0 = kc * 32 + ((lane >> 4) << 3);
  return *(const f16x8*)(base + (size_t)row * D + k0);
}

// Swizzled B-fragment: slot (t,kc) holds 64 lanes' f16x8 contiguously (1KB)
__device__ __forceinline__ f16x8 load_b_swz(const _Float16* __restrict__ W,
                                            int t, int kc, int lane) {
  return *(const f16x8*)(W + (((size_t)t * 3 + kc) * 64 + lane) * 8);
}

// ---------- one-time prep ----------

__global__ void prep_weights_kernel(const float* __restrict__ Wih,
                                    const float* __restrict__ Whh,
                                    const float* __restrict__ We,
                                    const float* __restrict__ be,
                                    _Float16* __restrict__ WxF,
                                    _Float16* __restrict__ WhhF,
                                    float* __restrict__ bxe) {
  int idx = blockIdx.x * blockDim.x + threadIdx.x;
  const int SWZ = 2 * NT * 3 * 64;   // 6912 swizzle threads
  if (idx < SWZ) {
    int mat = idx / (NT * 3 * 64);
    int rem = idx - mat * (NT * 3 * 64);
    int t = rem / (3 * 64);
    int rem2 = rem - t * (3 * 64);
    int kc = rem2 >> 6;
    int lane = rem2 & 63;
    int c = t * 16 + (lane & 15);
    int k0 = kc * 32 + ((lane >> 4) << 3);
    f16x8 o;
    if (mat == 0) {
      float a[8] = {0.f, 0.f, 0.f, 0.f, 0.f, 0.f, 0.f, 0.f};
      const float* wr = Wih + (size_t)c * D;
      for (int c2 = 0; c2 < D; ++c2) {
        float wv = wr[c2];
        const float* werow = We + (size_t)c2 * D + k0;
#pragma unroll
        for (int j = 0; j < 8; ++j) a[j] += wv * werow[j];
      }
#pragma unroll
      for (int j = 0; j < 8; ++j) o[j] = (_Float16)a[j];
      *(f16x8*)(WxF + (((size_t)t * 3 + kc) * 64 + lane) * 8) = o;
    } else {
#pragma unroll
      for (int j = 0; j < 8; ++j) o[j] = (_Float16)Whh[(size_t)c * D + k0 + j];
      *(f16x8*)(WhhF + (((size_t)t * 3 + kc) * 64 + lane) * 8) = o;
    }
  } else if (idx < SWZ + G3) {
    int r = idx - SWZ;
    float acc = 0.f;
    const float* wr = Wih + (size_t)r * D;
    for (int c = 0; c < D; ++c) acc += wr[c] * be[c];
    bxe[r] = acc;
  }
}

// ---------- CSR build (bucketed) ----------

__global__ void route_kernel(const int* __restrict__ src, const int* __restrict__ dst,
                             int* __restrict__ bucket_fill,
                             unsigned* __restrict__ stage, int E,
                             const float* __restrict__ x,
                             _Float16* __restrict__ hA, int total4) {
  __shared__ int cnt[64], gbase[64];
  int tid = threadIdx.x;              // 256
  int base = blockIdx.x * 1024;
  if (tid < 64) cnt[tid] = 0;
  __syncthreads();
  int b[4], lp[4], sv[4], dl[4];
#pragma unroll
  for (int j = 0; j < 4; ++j) {
    int e = base + tid * 4 + j;
    if (e < E) {
      sv[j] = src[e];
      int d = dst[e];
      b[j] = d >> 10;
      dl[j] = d & 1023;
      lp[j] = atomicAdd(&cnt[b[j]], 1);
    } else {
      b[j] = -1;
    }
  }
  __syncthreads();
  if (tid < 64) {
    int c = cnt[tid];
    gbase[tid] = (c > 0) ? atomicAdd(&bucket_fill[tid], c) : 0;
  }
  __syncthreads();
#pragma unroll
  for (int j = 0; j < 4; ++j) {
    if (b[j] >= 0) {
      int pos = b[j] * CAP + gbase[b[j]] + lp[j];
      stage[pos] = (unsigned)sv[j] | ((unsigned)dl[j] << 16);
    }
  }
  for (int i = blockIdx.x * blockDim.x + threadIdx.x; i < total4;
       i += gridDim.x * blockDim.x) {
    float4 v = ((const float4*)x)[i];
    f16x4 o;
    o[0] = (_Float16)v.x; o[1] = (_Float16)v.y;
    o[2] = (_Float16)v.z; o[3] = (_Float16)v.w;
    *(f16x4*)(hA + (size_t)i * 4) = o;
  }
}

__global__ void bucket_scan_kernel(const int* __restrict__ bucket_fill,
                                   int* __restrict__ bucket_base,
                                   int* __restrict__ row_ptr, int NB, int n, int E) {
  if (threadIdx.x == 0) {
    int run = 0;
    for (int i = 0; i < NB; ++i) { bucket_base[i] = run; run += bucket_fill[i]; }
    bucket_base[NB] = run;
    row_ptr[n] = E;
  }
}

__global__ void local_fill_kernel(const unsigned* __restrict__ stage,
                                  const int* __restrict__ bucket_fill,
                                  const int* __restrict__ bucket_base,
                                  int* __restrict__ row_ptr,
                                  unsigned short* __restrict__ csr_src, int n) {
  __shared__ int hc[1024];
  __shared__ int sc[1024];
  int b = blockIdx.x;
  int node0 = b << 10;
  int nn = n - node0; if (nn > 1024) nn = 1024;
  int tid = threadIdx.x;              // 1024
  int cnt_b = bucket_fill[b];
  int gb = bucket_base[b];
  const unsigned* sb = stage + (size_t)b * CAP;
  hc[tid] = 0;
  __syncthreads();
  for (int i = tid; i < cnt_b; i += 1024)
    atomicAdd(&hc[(int)(sb[i] >> 16)], 1);
  __syncthreads();
  sc[tid] = hc[tid];
  __syncthreads();
  for (int off = 1; off < 1024; off <<= 1) {
    int v = (tid >= off) ? sc[tid - off] : 0;
    __syncthreads();
    sc[tid] += v;
    __syncthreads();
  }
  int excl = sc[tid] - hc[tid];
  __syncthreads();
  sc[tid] = excl;
  if (tid < nn) row_ptr[node0 + tid] = gb + excl;
  hc[tid] = 0;
  __syncthreads();
  for (int i = tid; i < cnt_b; i += 1024) {
    unsigned p = sb[i];
    int dl = (int)(p >> 16);
    int pos = gb + sc[dl] + atomicAdd(&hc[dl], 1);
    csr_src[pos] = (unsigned short)(p & 0xFFFF);
  }
}

// ---------- fused per-step kernel ----------

// Phases 1-2 (gather + GEMM), shared by both step kernels.
// On return: acc0/acc1 hold the wave's two row-tile gate accumulators,
// plane = which LDS gate plane this wave stores to.
__device__ __forceinline__ void gru_compute(
    float* lds, _Float16* sl,
    const _Float16* __restrict__ h,
    const int* __restrict__ row_ptr, const unsigned short* __restrict__ csr_src,
    const _Float16* __restrict__ WxF, const _Float16* __restrict__ WhhF,
    int n, int r0, int tid, int w, int lane,
    f32x4 (&acc0)[6], f32x4 (&acc1)[6], int& plane) {
  // ---- phase 1: gather (12 threads/row, one f16x8 chunk each; 8-deep MLP) ----
  {
    int row = tid / 12;        // 0..31
    int part = tid - row * 12; // chunk of 8 fp16
    int grow = r0 + row;
    float acc[8];
#pragma unroll
    for (int j = 0; j < 8; ++j) acc[j] = 0.f;
    if (grow < n) {
      int beg = row_ptr[grow], end = row_ptr[grow + 1];
      const _Float16* hp = h + (size_t)part * 8;
      int e = beg;
      for (; e + 7 < end; e += 8) {
        f16x8 v0 = *(const f16x8*)(hp + (size_t)csr_src[e] * D);
        f16x8 v1 = *(const f16x8*)(hp + (size_t)csr_src[e + 1] * D);
        f16x8 v2 = *(const f16x8*)(hp + (size_t)csr_src[e + 2] * D);
        f16x8 v3 = *(const f16x8*)(hp + (size_t)csr_src[e + 3] * D);
        f16x8 v4 = *(const f16x8*)(hp + (size_t)csr_src[e + 4] * D);
        f16x8 v5 = *(const f16x8*)(hp + (size_t)csr_src[e + 5] * D);
        f16x8 v6 = *(const f16x8*)(hp + (size_t)csr_src[e + 6] * D);
        f16x8 v7 = *(const f16x8*)(hp + (size_t)csr_src[e + 7] * D);
#pragma unroll
        for (int j = 0; j < 8; ++j)
          acc[j] += (((float)v0[j] + (float)v1[j]) + ((float)v2[j] + (float)v3[j])) +
                    (((float)v4[j] + (float)v5[j]) + ((float)v6[j] + (float)v7[j]));
      }
      if (e + 3 < end) {
        f16x8 v0 = *(const f16x8*)(hp + (size_t)csr_src[e] * D);
        f16x8 v1 = *(const f16x8*)(hp + (size_t)csr_src[e + 1] * D);
        f16x8 v2 = *(const f16x8*)(hp + (size_t)csr_src[e + 2] * D);
        f16x8 v3 = *(const f16x8*)(hp + (size_t)csr_src[e + 3] * D);
#pragma unroll
        for (int j = 0; j < 8; ++j)
          acc[j] += ((float)v0[j] + (float)v1[j]) + ((float)v2[j] + (float)v3[j]);
        e += 4;
      }
      for (; e < end; ++e) {
        f16x8 v = *(const f16x8*)(hp + (size_t)csr_src[e] * D);
#pragma unroll
        for (int j = 0; j < 8; ++j) acc[j] += (float)v[j];
      }
    }
    f16x8 o;
#pragma unroll
    for (int j = 0; j < 8; ++j) o[j] = (_Float16)acc[j];
    *(f16x8*)&sl[row * SLP + part * 8] = o;
  }
  __syncthreads();

  // ---- phase 2: A-fragment loads + GEMM ----
  const int opS = (w < 3) ? 1 : 0;
  const _Float16* WF = opS ? WxF : WhhF;
  const int wg = opS ? w : (w - 3);        // 0=R, 1=Z, 2=N
  const int t0 = wg * 6;                   // col-tiles t0..t0+5
  plane = wg * 2 + (opS ? 0 : 1);

  f16x8 a0[3], a1[3];
  if (opS) {
#pragma unroll
    for (int kc = 0; kc < 3; ++kc) {
      int k0 = kc * 32 + ((lane >> 4) << 3);
      a0[kc] = *(const f16x8*)&sl[(lane & 15) * SLP + k0];
      a1[kc] = *(const f16x8*)&sl[(16 + (lane & 15)) * SLP + k0];
    }
  } else {
#pragma unroll
    for (int kc = 0; kc < 3; ++kc) {
      a0[kc] = load_a_frag(h, r0, lane, kc);
      a1[kc] = load_a_frag(h, r0 + 16, lane, kc);
    }
  }
  __syncthreads();   // sl fully read (in regs) before planes 4/5 are overwritten

#pragma unroll
  for (int t = 0; t < 6; ++t) {
    acc0[t] = (f32x4){0.f, 0.f, 0.f, 0.f};
    acc1[t] = (f32x4){0.f, 0.f, 0.f, 0.f};
  }
#pragma unroll
  for (int ct = 0; ct < 6; ++ct)
#pragma unroll
    for (int kc = 0; kc < 3; ++kc) {
      f16x8 b = load_b_swz(WF, t0 + ct, kc, lane);
      acc0[ct] = __builtin_amdgcn_mfma_f32_16x16x32_f16(a0[kc], b, acc0[ct], 0, 0, 0);
      acc1[ct] = __builtin_amdgcn_mfma_f32_16x16x32_f16(a1[kc], b, acc1[ct], 0, 0, 0);
    }
}

__device__ __forceinline__ void store_planes(float* lds, const f32x4 (&acc)[6],
                                             int plane, int lane) {
  int col_l = lane & 15;
  int rq = (lane >> 4) << 2;
#pragma unroll
  for (int ct = 0; ct < 6; ++ct)
#pragma unroll
    for (int q = 0; q < 4; ++q)
      lds[plane * PLANE + (rq + q) * PLS + ct * 16 + col_l] = acc[ct][q];
}

__device__ __forceinline__ void gru_epilogue(const float* lds,
                                             const _Float16* __restrict__ h,
                                             _Float16* __restrict__ hout,
                                             const int* __restrict__ row_ptr,
                                             const float* __restrict__ bxe,
                                             const float* __restrict__ bih,
                                             const float* __restrict__ bhh,
                                             int base_row, int tid) {
#pragma unroll
  for (int j = 0; j < 4; ++j) {
    int e = tid + j * 384;
    int row = e / D;
    int col = e - row * D;
    int grow = base_row + row;
    int a = row * PLS + col;
    float degf = (float)(row_ptr[grow + 1] - row_ptr[grow]);
    float R  = lds[a] + lds[PLANE + a];
    float Z  = lds[2 * PLANE + a] + lds[3 * PLANE + a];
    float XN = lds[4 * PLANE + a];
    float HN = lds[5 * PLANE + a];
    float rg = 1.0f / (1.0f + __expf(-(R + bih[col] + bhh[col] + degf * bxe[col])));
    float zg = 1.0f / (1.0f + __expf(-(Z + bih[D + col] + bhh[D + col] + degf * bxe[D + col])));
    float ng = tanhf(XN + bih[2 * D + col] + degf * bxe[2 * D + col] + rg * (HN + bhh[2 * D + col]));
    float hv = (float)h[(size_t)grow * D + col];
    hout[(size_t)grow * D + col] = (_Float16)((1.0f - zg) * ng + zg * hv);
  }
}

// Same as gru_epilogue but writes elu(h') into an LDS tile (no global write).
__device__ __forceinline__ void gru_epilogue_elu(const float* lds,
                                                 _Float16* eluh,
                                                 const _Float16* __restrict__ h,
                                                 const int* __restrict__ row_ptr,
                                                 const float* __restrict__ bxe,
                                                 const float* __restrict__ bih,
                                                 const float* __restrict__ bhh,
                                                 int base_row, int erow0, int tid) {
#pragma unroll
  for (int j = 0; j < 4; ++j) {
    int e = tid + j * 384;
    int row = e / D;
    int col = e - row * D;
    int grow = base_row + row;
    int a = row * PLS + col;
    float degf = (float)(row_ptr[grow + 1] - row_ptr[grow]);
    float R  = lds[a] + lds[PLANE + a];
    float Z  = lds[2 * PLANE + a] + lds[3 * PLANE + a];
    float XN = lds[4 * PLANE + a];
    float HN = lds[5 * PLANE + a];
    float rg = 1.0f / (1.0f + __expf(-(R + bih[col] + bhh[col] + degf * bxe[col])));
    float zg = 1.0f / (1.0f + __expf(-(Z + bih[D + col] + bhh[D + col] + degf * bxe[D + col])));
    float ng = tanhf(XN + bih[2 * D + col] + degf * bxe[2 * D + col] + rg * (HN + bhh[2 * D + col]));
    float hv = (float)h[(size_t)grow * D + col];
    float hn2 = (1.0f - zg) * ng + zg * hv;
    float el = hn2 > 0.0f ? hn2 : (__expf(hn2) - 1.0f);
    eluh[(erow0 + row) * ELP + col] = (_Float16)el;
  }
}

__global__ __launch_bounds__(384) void gru_fused_kernel(
    const _Float16* __restrict__ h, _Float16* __restrict__ hout,
    const int* __restrict__ row_ptr, const unsigned short* __restrict__ csr_src,
    const _Float16* __restrict__ WxF, const _Float16* __restrict__ WhhF,
    const float* __restrict__ bxe, const float* __restrict__ bih,
    const float* __restrict__ bhh, int n) {
  __shared__ float lds[6 * PLANE];                    // 37.2 KB
  _Float16* sl = (_Float16*)&lds[4 * PLANE];          // s tile aliases planes 4/5
  int r0 = blockIdx.x << 5;
  int tid = threadIdx.x;
  int w = tid >> 6;
  int lane = tid & 63;
  f32x4 acc0[6], acc1[6];
  int plane;
  gru_compute(lds, sl, h, row_ptr, csr_src, WxF, WhhF, n, r0, tid, w, lane,
              acc0, acc1, plane);
  store_planes(lds, acc0, plane, lane);
  __syncthreads();
  gru_epilogue(lds, h, hout, row_ptr, bxe, bih, bhh, r0, tid);
  __syncthreads();
  if (r0 + 16 < n) {
    store_planes(lds, acc1, plane, lane);
    __syncthreads();
    gru_epilogue(lds, h, hout, row_ptr, bxe, bih, bhh, r0 + 16, tid);
  }
}

// Last step: fused classifier head. elu(h') staged in LDS; logits written directly.
__global__ __launch_bounds__(384) void gru_fused_last_kernel(
    const _Float16* __restrict__ h,
    const int* __restrict__ row_ptr, const unsigned short* __restrict__ csr_src,
    const _Float16* __restrict__ WxF, const _Float16* __restrict__ WhhF,
    const float* __restrict__ bxe, const float* __restrict__ bih,
    const float* __restrict__ bhh,
    const float* __restrict__ Wfc, const float* __restrict__ bfc,
    float* __restrict__ out, int n, int C) {
  __shared__ float lds[6 * PLANE];                    // 37.2 KB
  __shared__ _Float16 eluh[32 * ELP];                 // 6.4 KB elu(h') tile
  _Float16* sl = (_Float16*)&lds[4 * PLANE];
  int r0 = blockIdx.x << 5;
  int tid = threadIdx.x;
  int w = tid >> 6;
  int lane = tid & 63;
  f32x4 acc0[6], acc1[6];
  int plane;
  gru_compute(lds, sl, h, row_ptr, csr_src, WxF, WhhF, n, r0, tid, w, lane,
              acc0, acc1, plane);
  store_planes(lds, acc0, plane, lane);
  __syncthreads();
  gru_epilogue_elu(lds, eluh, h, row_ptr, bxe, bih, bhh, r0, 0, tid);
  __syncthreads();
  if (r0 + 16 < n) {
    store_planes(lds, acc1, plane, lane);
    __syncthreads();
    gru_epilogue_elu(lds, eluh, h, row_ptr, bxe, bih, bhh, r0 + 16, 16, tid);
  }
  __syncthreads();
  // head: 320 threads compute logits for this block's 32 rows x C classes
  if (tid < 32 * C) {
    int row = tid / C;
    int c = tid - row * C;
    int grow = r0 + row;
    if (grow < n) {
      const _Float16* er = &eluh[row * ELP];
      const float* wr = Wfc + (size_t)c * D;
      float acc = bfc[c];
#pragma unroll 8
      for (int k = 0; k < D; ++k) acc += (float)er[k] * wr[k];
      out[(size_t)grow * C + c] = acc;
    }
  }
}

extern "C" void kernel_launch(void* const* d_in, const int* in_sizes, int n_in,
                              void* d_out, int out_size, void* d_ws, size_t ws_size,
                              hipStream_t stream) {
  const float* x    = (const float*)d_in[0];
  const int*   src  = (const int*)d_in[1];
  const int*   dst  = (const int*)d_in[2];
  const float* W_e  = (const float*)d_in[3];
  const float* b_e  = (const float*)d_in[4];
  const float* W_ih = (const float*)d_in[5];
  const float* W_hh = (const float*)d_in[6];
  const float* b_ih = (const float*)d_in[7];
  const float* b_hh = (const float*)d_in[8];
  const float* W_fc = (const float*)d_in[9];
  const float* b_fc = (const float*)d_in[10];

  const int n = in_sizes[0] / D;   // 50000
  const int E = in_sizes[1];       // 800000
  const int C = out_size / n;      // 10

  // ws layout:
  _Float16* hA = (_Float16*)d_ws;                 // n*D fp16
  _Float16* hB = hA + (size_t)n * D;              // n*D fp16
  _Float16* WxF  = hB + (size_t)n * D;            // G3*D fp16 swizzled
  _Float16* WhhF = WxF + (size_t)G3 * D;
  float* bxe   = (float*)(WhhF + (size_t)G3 * D); // G3 fp32
  int* bucket_fill = (int*)(bxe + G3);            // 64
  int* bucket_base = bucket_fill + 64;            // 65
  int* row_ptr = bucket_base + 65;                // n+1
  unsigned short* csr_src = (unsigned short*)(row_ptr + (n + 1));  // E u16
  unsigned* stage = (unsigned*)(csr_src + E);     // NB*CAP u32

  const int threads = 256;
  const int NB = (n + 1023) >> 10;                // 49 dst buckets
  const int total4 = n * D / 4;

  (void)hipMemsetAsync(bucket_fill, 0, 64 * sizeof(int), stream);
  route_kernel<<<(E + 1023) / 1024, 256, 0, stream>>>(src, dst, bucket_fill,
                                                      stage, E, x, hA, total4);
  bucket_scan_kernel<<<1, 64, 0, stream>>>(bucket_fill, bucket_base, row_ptr,
                                           NB, n, E);
  local_fill_kernel<<<NB, 1024, 0, stream>>>(stage, bucket_fill, bucket_base,
                                             row_ptr, csr_src, n);
  prep_weights_kernel<<<(2 * NT * 3 * 64 + G3 + threads - 1) / threads, threads, 0,
                        stream>>>(W_ih, W_hh, W_e, b_e, WxF, WhhF, bxe);

  const int gridG = (n + 31) / 32;   // 32 rows per block

  const _Float16* hcur = hA;
  _Float16* hnext = hB;
  for (int step = 0; step < NSTEPS - 1; ++step) {
    gru_fused_kernel<<<gridG, 384, 0, stream>>>(hcur, hnext, row_ptr, csr_src,
                                                WxF, WhhF, bxe, b_ih, b_hh, n);
    const _Float16* t = hcur; hcur = hnext; hnext = (_Float16*)t;
  }
  gru_fused_last_kernel<<<gridG, 384, 0, stream>>>(hcur, row_ptr, csr_src,
                                                   WxF, WhhF, bxe, b_ih, b_hh,
                                                   W_fc, b_fc, (float*)d_out, n, C);
}

// Round 20
// 300.751 us; speedup vs baseline: 1.0172x; 1.0172x over previous
//
#include <hip/hip_runtime.h>

static constexpr int D = 96;       // hidden size
static constexpr int G3 = 3 * D;   // 288 gate rows
static constexpr int NSTEPS = 4;   // GGNN propagation steps
static constexpr int NT = 18;      // 288/16 col-tiles per weight matrix
static constexpr int SLP = 104;    // s-tile LDS row pad (fp16)
static constexpr int PLS = 97;     // plane row stride (dwords)
static constexpr int PLANE = 16 * PLS;
static constexpr int CAP = 24576;  // staging capacity per 1024-node bucket

typedef __attribute__((ext_vector_type(8))) _Float16 f16x8;  // 8 fp16 (4 VGPRs)
typedef __attribute__((ext_vector_type(4))) _Float16 f16x4;
typedef __attribute__((ext_vector_type(4))) float f32x4;     // MFMA C/D frag

// A-fragment for mfma_f32_16x16x32_f16 from fp16 row-major [*,96]
__device__ __forceinline__ f16x8 load_a_frag(const _Float16* __restrict__ base,
                                             int r0, int lane, int kc) {
  int row = r0 + (lane & 15);
  int k0 = kc * 32 + ((lane >> 4) << 3);
  return *(const f16x8*)(base + (size_t)row * D + k0);
}

// Swizzled B-fragment: slot (t,kc) holds 64 lanes' f16x8 contiguously (1KB)
__device__ __forceinline__ f16x8 load_b_swz(const _Float16* __restrict__ W,
                                            int t, int kc, int lane) {
  return *(const f16x8*)(W + (((size_t)t * 3 + kc) * 64 + lane) * 8);
}

// ---------- one-time prep ----------

__global__ void prep_weights_kernel(const float* __restrict__ Wih,
                                    const float* __restrict__ Whh,
                                    const float* __restrict__ We,
                                    const float* __restrict__ be,
                                    _Float16* __restrict__ WxF,
                                    _Float16* __restrict__ WhhF,
                                    float* __restrict__ bxe) {
  int idx = blockIdx.x * blockDim.x + threadIdx.x;
  const int SWZ = 2 * NT * 3 * 64;   // 6912 swizzle threads
  if (idx < SWZ) {
    int mat = idx / (NT * 3 * 64);
    int rem = idx - mat * (NT * 3 * 64);
    int t = rem / (3 * 64);
    int rem2 = rem - t * (3 * 64);
    int kc = rem2 >> 6;
    int lane = rem2 & 63;
    int c = t * 16 + (lane & 15);
    int k0 = kc * 32 + ((lane >> 4) << 3);
    f16x8 o;
    if (mat == 0) {
      float a[8] = {0.f, 0.f, 0.f, 0.f, 0.f, 0.f, 0.f, 0.f};
      const float* wr = Wih + (size_t)c * D;
      for (int c2 = 0; c2 < D; ++c2) {
        float wv = wr[c2];
        const float* werow = We + (size_t)c2 * D + k0;
#pragma unroll
        for (int j = 0; j < 8; ++j) a[j] += wv * werow[j];
      }
#pragma unroll
      for (int j = 0; j < 8; ++j) o[j] = (_Float16)a[j];
      *(f16x8*)(WxF + (((size_t)t * 3 + kc) * 64 + lane) * 8) = o;
    } else {
#pragma unroll
      for (int j = 0; j < 8; ++j) o[j] = (_Float16)Whh[(size_t)c * D + k0 + j];
      *(f16x8*)(WhhF + (((size_t)t * 3 + kc) * 64 + lane) * 8) = o;
    }
  } else if (idx < SWZ + G3) {
    int r = idx - SWZ;
    float acc = 0.f;
    const float* wr = Wih + (size_t)r * D;
    for (int c = 0; c < D; ++c) acc += wr[c] * be[c];
    bxe[r] = acc;
  }
}

// ---------- CSR build (bucketed; no global hist/scan needed) ----------

// Route edges into fixed-capacity per-bucket staging regions (b*CAP).
// Tail: grid-stride convert of x -> fp16 h.
__global__ void route_kernel(const int* __restrict__ src, const int* __restrict__ dst,
                             int* __restrict__ bucket_fill,
                             unsigned* __restrict__ stage, int E,
                             const float* __restrict__ x,
                             _Float16* __restrict__ hA, int total4) {
  __shared__ int cnt[64], gbase[64];
  int tid = threadIdx.x;              // 256
  int base = blockIdx.x * 1024;
  if (tid < 64) cnt[tid] = 0;
  __syncthreads();
  int b[4], lp[4], sv[4], dl[4];
#pragma unroll
  for (int j = 0; j < 4; ++j) {
    int e = base + tid * 4 + j;
    if (e < E) {
      sv[j] = src[e];
      int d = dst[e];
      b[j] = d >> 10;
      dl[j] = d & 1023;
      lp[j] = atomicAdd(&cnt[b[j]], 1);
    } else {
      b[j] = -1;
    }
  }
  __syncthreads();
  if (tid < 64) {
    int c = cnt[tid];
    gbase[tid] = (c > 0) ? atomicAdd(&bucket_fill[tid], c) : 0;
  }
  __syncthreads();
#pragma unroll
  for (int j = 0; j < 4; ++j) {
    if (b[j] >= 0) {
      int pos = b[j] * CAP + gbase[b[j]] + lp[j];
      stage[pos] = (unsigned)sv[j] | ((unsigned)dl[j] << 16);
    }
  }
  // tail: convert x (fp32) -> hA (fp16)
  for (int i = blockIdx.x * blockDim.x + threadIdx.x; i < total4;
       i += gridDim.x * blockDim.x) {
    float4 v = ((const float4*)x)[i];
    f16x4 o;
    o[0] = (_Float16)v.x; o[1] = (_Float16)v.y;
    o[2] = (_Float16)v.z; o[3] = (_Float16)v.w;
    *(f16x4*)(hA + (size_t)i * 4) = o;
  }
}

// Tiny serial scan of bucket counts -> bucket bases; also row_ptr[n] = E.
__global__ void bucket_scan_kernel(const int* __restrict__ bucket_fill,
                                   int* __restrict__ bucket_base,
                                   int* __restrict__ row_ptr, int NB, int n, int E) {
  if (threadIdx.x == 0) {
    int run = 0;
    for (int i = 0; i < NB; ++i) { bucket_base[i] = run; run += bucket_fill[i]; }
    bucket_base[NB] = run;
    row_ptr[n] = E;
  }
}

// Per bucket: LDS histogram of staged edges -> LDS scan -> write row_ptr
// segment AND scatter csr_src, all with LDS counters (csr window L2-local).
__global__ void local_fill_kernel(const unsigned* __restrict__ stage,
                                  const int* __restrict__ bucket_fill,
                                  const int* __restrict__ bucket_base,
                                  int* __restrict__ row_ptr,
                                  unsigned short* __restrict__ csr_src, int n) {
  __shared__ int hc[1024];
  __shared__ int sc[1024];
  int b = blockIdx.x;
  int node0 = b << 10;
  int nn = n - node0; if (nn > 1024) nn = 1024;
  int tid = threadIdx.x;              // 1024
  int cnt_b = bucket_fill[b];
  int gb = bucket_base[b];
  const unsigned* sb = stage + (size_t)b * CAP;
  hc[tid] = 0;
  __syncthreads();
  for (int i = tid; i < cnt_b; i += 1024)
    atomicAdd(&hc[(int)(sb[i] >> 16)], 1);
  __syncthreads();
  sc[tid] = hc[tid];
  __syncthreads();
  for (int off = 1; off < 1024; off <<= 1) {
    int v = (tid >= off) ? sc[tid - off] : 0;
    __syncthreads();
    sc[tid] += v;
    __syncthreads();
  }
  int excl = sc[tid] - hc[tid];
  __syncthreads();
  sc[tid] = excl;
  if (tid < nn) row_ptr[node0 + tid] = gb + excl;
  hc[tid] = 0;
  __syncthreads();
  for (int i = tid; i < cnt_b; i += 1024) {
    unsigned p = sb[i];
    int dl = (int)(p >> 16);
    int pos = gb + sc[dl] + atomicAdd(&hc[dl], 1);
    csr_src[pos] = (unsigned short)(p & 0xFFFF);
  }
}

// ---------- fused per-step kernel (R12/R15 config: best measured, 57.5us) ----------

__device__ __forceinline__ void gru_epilogue(const float* lds,
                                             const _Float16* __restrict__ h,
                                             _Float16* __restrict__ hout,
                                             const int* __restrict__ row_ptr,
                                             const float* __restrict__ bxe,
                                             const float* __restrict__ bih,
                                             const float* __restrict__ bhh,
                                             int base_row, int tid) {
#pragma unroll
  for (int j = 0; j < 4; ++j) {
    int e = tid + j * 384;
    int row = e / D;
    int col = e - row * D;
    int grow = base_row + row;
    int a = row * PLS + col;
    float degf = (float)(row_ptr[grow + 1] - row_ptr[grow]);
    float R  = lds[a] + lds[PLANE + a];
    float Z  = lds[2 * PLANE + a] + lds[3 * PLANE + a];
    float XN = lds[4 * PLANE + a];
    float HN = lds[5 * PLANE + a];
    float rg = 1.0f / (1.0f + __expf(-(R + bih[col] + bhh[col] + degf * bxe[col])));
    float zg = 1.0f / (1.0f + __expf(-(Z + bih[D + col] + bhh[D + col] + degf * bxe[D + col])));
    float ng = tanhf(XN + bih[2 * D + col] + degf * bxe[2 * D + col] + rg * (HN + bhh[2 * D + col]));
    float hv = (float)h[(size_t)grow * D + col];
    hout[(size_t)grow * D + col] = (_Float16)((1.0f - zg) * ng + zg * hv);
  }
}

__global__ __launch_bounds__(384) void gru_fused_kernel(
    const _Float16* __restrict__ h, _Float16* __restrict__ hout,
    const int* __restrict__ row_ptr, const unsigned short* __restrict__ csr_src,
    const _Float16* __restrict__ WxF, const _Float16* __restrict__ WhhF,
    const float* __restrict__ bxe, const float* __restrict__ bih,
    const float* __restrict__ bhh, int n) {
  __shared__ float lds[6 * PLANE];                    // 37.2 KB total
  _Float16* sl = (_Float16*)&lds[4 * PLANE];          // s tile aliases planes 4/5
  int r0 = blockIdx.x << 5;   // 32 rows per block
  int tid = threadIdx.x;
  int w = tid >> 6;
  int lane = tid & 63;

  // ---- phase 1: gather (12 threads/row, one f16x8 chunk each; 8-deep MLP) ----
  {
    int row = tid / 12;        // 0..31
    int part = tid - row * 12; // chunk of 8 fp16
    int grow = r0 + row;
    float acc[8];
#pragma unroll
    for (int j = 0; j < 8; ++j) acc[j] = 0.f;
    if (grow < n) {
      int beg = row_ptr[grow], end = row_ptr[grow + 1];
      const _Float16* hp = h + (size_t)part * 8;
      int e = beg;
      for (; e + 7 < end; e += 8) {
        f16x8 v0 = *(const f16x8*)(hp + (size_t)csr_src[e] * D);
        f16x8 v1 = *(const f16x8*)(hp + (size_t)csr_src[e + 1] * D);
        f16x8 v2 = *(const f16x8*)(hp + (size_t)csr_src[e + 2] * D);
        f16x8 v3 = *(const f16x8*)(hp + (size_t)csr_src[e + 3] * D);
        f16x8 v4 = *(const f16x8*)(hp + (size_t)csr_src[e + 4] * D);
        f16x8 v5 = *(const f16x8*)(hp + (size_t)csr_src[e + 5] * D);
        f16x8 v6 = *(const f16x8*)(hp + (size_t)csr_src[e + 6] * D);
        f16x8 v7 = *(const f16x8*)(hp + (size_t)csr_src[e + 7] * D);
#pragma unroll
        for (int j = 0; j < 8; ++j)
          acc[j] += (((float)v0[j] + (float)v1[j]) + ((float)v2[j] + (float)v3[j])) +
                    (((float)v4[j] + (float)v5[j]) + ((float)v6[j] + (float)v7[j]));
      }
      if (e + 3 < end) {
        f16x8 v0 = *(const f16x8*)(hp + (size_t)csr_src[e] * D);
        f16x8 v1 = *(const f16x8*)(hp + (size_t)csr_src[e + 1] * D);
        f16x8 v2 = *(const f16x8*)(hp + (size_t)csr_src[e + 2] * D);
        f16x8 v3 = *(const f16x8*)(hp + (size_t)csr_src[e + 3] * D);
#pragma unroll
        for (int j = 0; j < 8; ++j)
          acc[j] += ((float)v0[j] + (float)v1[j]) + ((float)v2[j] + (float)v3[j]);
        e += 4;
      }
      for (; e < end; ++e) {
        f16x8 v = *(const f16x8*)(hp + (size_t)csr_src[e] * D);
#pragma unroll
        for (int j = 0; j < 8; ++j) acc[j] += (float)v[j];
      }
    }
    f16x8 o;
#pragma unroll
    for (int j = 0; j < 8; ++j) o[j] = (_Float16)acc[j];
    *(f16x8*)&sl[row * SLP + part * 8] = o;
  }
  __syncthreads();

  // ---- phase 2: A-fragment loads ----
  const int opS = (w < 3) ? 1 : 0;
  const _Float16* WF = opS ? WxF : WhhF;
  const int wg = opS ? w : (w - 3);        // 0=R, 1=Z, 2=N
  const int t0 = wg * 6;                   // col-tiles t0..t0+5
  const int plane = wg * 2 + (opS ? 0 : 1);

  f16x8 a0[3], a1[3];
  if (opS) {
#pragma unroll
    for (int kc = 0; kc < 3; ++kc) {
      int k0 = kc * 32 + ((lane >> 4) << 3);
      a0[kc] = *(const f16x8*)&sl[(lane & 15) * SLP + k0];
      a1[kc] = *(const f16x8*)&sl[(16 + (lane & 15)) * SLP + k0];
    }
  } else {
#pragma unroll
    for (int kc = 0; kc < 3; ++kc) {
      a0[kc] = load_a_frag(h, r0, lane, kc);
      a1[kc] = load_a_frag(h, r0 + 16, lane, kc);
    }
  }
  __syncthreads();   // sl fully read (in regs) before planes 4/5 are overwritten

  f32x4 acc0[6], acc1[6];
#pragma unroll
  for (int t = 0; t < 6; ++t) {
    acc0[t] = (f32x4){0.f, 0.f, 0.f, 0.f};
    acc1[t] = (f32x4){0.f, 0.f, 0.f, 0.f};
  }

#pragma unroll
  for (int ct = 0; ct < 6; ++ct)
#pragma unroll
    for (int kc = 0; kc < 3; ++kc) {
      f16x8 b = load_b_swz(WF, t0 + ct, kc, lane);
      acc0[ct] = __builtin_amdgcn_mfma_f32_16x16x32_f16(a0[kc], b, acc0[ct], 0, 0, 0);
      acc1[ct] = __builtin_amdgcn_mfma_f32_16x16x32_f16(a1[kc], b, acc1[ct], 0, 0, 0);
    }

  // ---- phase 3: epilogues (C/D layout: col=lane&15, row=(lane>>4)*4+q) ----
  int col_l = lane & 15;
  int rq = (lane >> 4) << 2;
#pragma unroll
  for (int ct = 0; ct < 6; ++ct)
#pragma unroll
    for (int q = 0; q < 4; ++q)
      lds[plane * PLANE + (rq + q) * PLS + ct * 16 + col_l] = acc0[ct][q];
  __syncthreads();
  gru_epilogue(lds, h, hout, row_ptr, bxe, bih, bhh, r0, tid);
  __syncthreads();
  if (r0 + 16 < n) {
#pragma unroll
    for (int ct = 0; ct < 6; ++ct)
#pragma unroll
      for (int q = 0; q < 4; ++q)
        lds[plane * PLANE + (rq + q) * PLS + ct * 16 + col_l] = acc1[ct][q];
    __syncthreads();
    gru_epilogue(lds, h, hout, row_ptr, bxe, bih, bhh, r0 + 16, tid);
  }
}

// logits[i,c] = sum_k elu(h[i,k]) * Wfc[c,k] + bfc[c]
__global__ void head_kernel(const _Float16* __restrict__ h,
                            const float* __restrict__ Wfc,
                            const float* __restrict__ bfc,
                            float* __restrict__ out,
                            int n, int C) {
  int idx = blockIdx.x * blockDim.x + threadIdx.x;
  if (idx >= n * C) return;
  int i = idx / C;
  int c = idx - i * C;
  const _Float16* hr = h + (size_t)i * D;
  const float* wr = Wfc + (size_t)c * D;
  float acc = bfc[c];
#pragma unroll 8
  for (int k = 0; k < D; ++k) {
    float hv = (float)hr[k];
    float e = hv > 0.0f ? hv : (__expf(hv) - 1.0f);
    acc += e * wr[k];
  }
  out[idx] = acc;
}

extern "C" void kernel_launch(void* const* d_in, const int* in_sizes, int n_in,
                              void* d_out, int out_size, void* d_ws, size_t ws_size,
                              hipStream_t stream) {
  const float* x    = (const float*)d_in[0];
  const int*   src  = (const int*)d_in[1];
  const int*   dst  = (const int*)d_in[2];
  const float* W_e  = (const float*)d_in[3];
  const float* b_e  = (const float*)d_in[4];
  const float* W_ih = (const float*)d_in[5];
  const float* W_hh = (const float*)d_in[6];
  const float* b_ih = (const float*)d_in[7];
  const float* b_hh = (const float*)d_in[8];
  const float* W_fc = (const float*)d_in[9];
  const float* b_fc = (const float*)d_in[10];

  const int n = in_sizes[0] / D;   // 50000
  const int E = in_sizes[1];       // 800000
  const int C = out_size / n;      // 10

  // ws layout:
  _Float16* hA = (_Float16*)d_ws;                 // n*D fp16
  _Float16* hB = hA + (size_t)n * D;              // n*D fp16
  _Float16* WxF  = hB + (size_t)n * D;            // G3*D fp16 swizzled
  _Float16* WhhF = WxF + (size_t)G3 * D;
  float* bxe   = (float*)(WhhF + (size_t)G3 * D); // G3 fp32
  int* bucket_fill = (int*)(bxe + G3);            // 64
  int* bucket_base = bucket_fill + 64;            // 65
  int* row_ptr = bucket_base + 65;                // n+1
  unsigned short* csr_src = (unsigned short*)(row_ptr + (n + 1));  // E u16
  unsigned* stage = (unsigned*)(csr_src + E);     // NB*CAP u32

  const int threads = 256;
  const int NB = (n + 1023) >> 10;                // 49 dst buckets
  const int total4 = n * D / 4;

  (void)hipMemsetAsync(bucket_fill, 0, 64 * sizeof(int), stream);
  route_kernel<<<(E + 1023) / 1024, 256, 0, stream>>>(src, dst, bucket_fill,
                                                      stage, E, x, hA, total4);
  bucket_scan_kernel<<<1, 64, 0, stream>>>(bucket_fill, bucket_base, row_ptr,
                                           NB, n, E);
  local_fill_kernel<<<NB, 1024, 0, stream>>>(stage, bucket_fill, bucket_base,
                                             row_ptr, csr_src, n);
  prep_weights_kernel<<<(2 * NT * 3 * 64 + G3 + threads - 1) / threads, threads, 0,
                        stream>>>(W_ih, W_hh, W_e, b_e, WxF, WhhF, bxe);

  const int gridG = (n + 31) / 32;   // 32 rows per block

  const _Float16* hcur = hA;
  _Float16* hnext = hB;
  for (int step = 0; step < NSTEPS; ++step) {
    gru_fused_kernel<<<gridG, 384, 0, stream>>>(hcur, hnext, row_ptr, csr_src,
                                                WxF, WhhF, bxe, b_ih, b_hh, n);
    const _Float16* t = hcur; hcur = hnext; hnext = (_Float16*)t;
  }

  const int gridH = (n * C + threads - 1) / threads;
  head_kernel<<<gridH, threads, 0, stream>>>(hcur, W_fc, b_fc, (float*)d_out, n, C);
}